// Round 12
// baseline (188.131 us; speedup 1.0000x reference)
//
#include <hip/hip_runtime.h>
#include <hip/hip_bf16.h>
#include <math.h>

#define BB 16
#define NN 16384
#define DD 256
#define KK 32

typedef short bf16x8 __attribute__((ext_vector_type(8)));
typedef float f32x4 __attribute__((ext_vector_type(4)));

__device__ inline unsigned pk2(float lo, float hi) {
    __hip_bfloat162 h = __float22bfloat162_rn(make_float2(lo, hi));
    union { __hip_bfloat162 h; unsigned u; } v; v.h = h;
    return v.u;
}
__device__ inline bf16x8 u4bf(uint4 q) {
    union { uint4 u; bf16x8 v; } c; c.u = q; return c.v;
}

// intra-wave LDS drain + scheduler fence (rule #18)
#define KWAIT() do { asm volatile("s_waitcnt lgkmcnt(0)" ::: "memory"); \
                     __builtin_amdgcn_sched_barrier(0); } while (0)

// compile-time float4 component select
#define CAE(vv, e) ((e) == 0 ? (vv).x : (e) == 1 ? (vv).y : (e) == 2 ? (vv).z : (vv).w)

// PROBE (r9 pattern): r11 kernel with the compute body run TWICE (pass 0
// discarded-equal, pass 1 final; acc/asr/af re-zeroed per pass -> output
// bit-identical). k1 ~190-200us surfaces above the 155us harness fills in the
// rocprof top-5, yielding the first counter row for the r11 structure:
// spill check (WRITE vs 68MB), bank conflicts, VALUBusy, occupancy.
__launch_bounds__(256, 2)
__global__ void netvlad_k1(const float* __restrict__ x,
                           const float* __restrict__ W,
                           const float* __restrict__ bias,
                           float* __restrict__ vpart,
                           float* __restrict__ apart) {
    __shared__ __align__(16) char lds[33280];
    // [0,16384):     Wl bf16, byte = k*512 + (dbyte ^ ((k&7)<<4))
    // [16384,32768): xt per-wave 4KB: d_local*32 + (nbyte ^ (((d_local>>3)&1)<<4))
    // epilogue: vbuf f32 [32][260] at byte 0 (33280 B)

    const int t   = threadIdx.x;
    const int l   = t & 63;
    const int w   = t >> 6;
    const int rg  = w >> 1;            // row-group: rows rg*16..+15 of each sub
    const int dh  = w & 1;             // d-half: [dh*128, dh*128+128)
    const int l15 = l & 15;
    const int lg4 = l >> 4;
    const int bid = blockIdx.x;
    const int b   = bid >> 6;          // batch
    const int blk = bid & 63;          // 256-row chunk

    // ---- stage Wl (bf16, swizzled) once ----
    for (int i = 0; i < 8; i++) {
        int f = i * 256 + t;           // float4 index in [0,2048)
        int k = f >> 6, c4 = f & 63;
        float4 wv = ((const float4*)W)[f];
        int byte = k * 512 + ((c4 * 8) ^ ((k & 7) << 4));
        *(uint2*)(lds + byte) = make_uint2(pk2(wv.x, wv.y), pk2(wv.z, wv.w));
    }
    const float cb0 = bias[l15];
    const float cb1 = bias[16 + l15];
    __syncthreads();                   // once; Wl read-only afterwards

    char* xtw = lds + 16384 + w * 4096;

    f32x4 acc0[8], acc1[8];
    float asr0, asr1;
    const float* xbase = x + ((size_t)b * NN + (size_t)blk * 256) * DD;
    const int rh = l >> 5;             // ca row-half (0..1)
    const int cl = l & 31;             // ca col slot

#pragma unroll 1
    for (int pass = 0; pass < 2; ++pass) {
#pragma unroll
        for (int i = 0; i < 8; i++) { acc0[i] = (f32x4){0,0,0,0}; acc1[i] = (f32x4){0,0,0,0}; }
        asr0 = 0.f; asr1 = 0.f;

        // prologue: prefetch sub-0 row-slices
        float4 pf[16];
        {
            const float* xr = xbase + (size_t)(rg * 16 + l15) * DD + lg4 * 8;
#pragma unroll
            for (int ks = 0; ks < 8; ks++) {
                pf[2 * ks]     = *(const float4*)(xr + ks * 32);
                pf[2 * ks + 1] = *(const float4*)(xr + ks * 32 + 4);
            }
        }

        uint4 af0 = make_uint4(0, 0, 0, 0), af1 = make_uint4(0, 0, 0, 0);

#pragma unroll 1
        for (int s = 0; s < 8; s++) {
            const float* xsub = xbase + ((size_t)s * 32 + (size_t)rg * 16) * DD;

            // A: issue ca col-loads — 8 rows (rh half) x 4 cols of own d-half
            float4 ca[8];
#pragma unroll
            for (int i = 0; i < 8; i++)
                ca[i] = *(const float4*)(xsub + (size_t)(rh * 8 + i) * DD + dh * 128 + cl * 4);

            // B: deferred aggregation for sub s-1 (covers ca latency)
            if (s > 0) {
                KWAIT();
#pragma unroll
                for (int dt = 0; dt < 8; dt++) {
                    int dl = dt * 16 + l15;
                    unsigned sw = ((unsigned)(dl >> 3) & 1u) << 4;
                    uint2 blv = *(const uint2*)(xtw + dl * 32 + ((lg4 * 8) ^ sw));
                    bf16x8 bv = u4bf(make_uint4(blv.x, blv.y, 0, 0));
                    acc0[dt] = __builtin_amdgcn_mfma_f32_16x16x32_bf16(u4bf(af0), bv, acc0[dt], 0, 0, 0);
                    acc1[dt] = __builtin_amdgcn_mfma_f32_16x16x32_bf16(u4bf(af1), bv, acc1[dt], 0, 0, 0);
                }
            }

            // C/D: stage wave-private x^T quarter-tile (128 d x 16 n bf16)
#pragma unroll
            for (int e = 0; e < 4; e++) {
                int dl = cl * 4 + e;
                unsigned sw = ((unsigned)(dl >> 3) & 1u) << 4;
                uint4 q;
                q.x = pk2(CAE(ca[0], e), CAE(ca[1], e));
                q.y = pk2(CAE(ca[2], e), CAE(ca[3], e));
                q.z = pk2(CAE(ca[4], e), CAE(ca[5], e));
                q.w = pk2(CAE(ca[6], e), CAE(ca[7], e));
                *(uint4*)(xtw + dl * 32 + (((unsigned)(rh * 16)) ^ sw)) = q;
            }

            // E: logits mfma(A = x row-frags from pf, B = W^T from Wl)
            f32x4 c0 = (f32x4){cb0, cb0, cb0, cb0};
            f32x4 c1 = (f32x4){cb1, cb1, cb1, cb1};
            {
                const unsigned swk = ((unsigned)(l15 & 7)) << 4;
#pragma unroll
                for (int ks = 0; ks < 8; ks++) {
                    uint4 xq;
                    xq.x = pk2(pf[2 * ks].x,     pf[2 * ks].y);
                    xq.y = pk2(pf[2 * ks].z,     pf[2 * ks].w);
                    xq.z = pk2(pf[2 * ks + 1].x, pf[2 * ks + 1].y);
                    xq.w = pk2(pf[2 * ks + 1].z, pf[2 * ks + 1].w);
                    bf16x8 ax = u4bf(xq);
                    bf16x8 w0 = *(const bf16x8*)(lds + l15 * 512        + (((unsigned)(ks * 64 + lg4 * 16)) ^ swk));
                    bf16x8 w1 = *(const bf16x8*)(lds + (16 + l15) * 512 + (((unsigned)(ks * 64 + lg4 * 16)) ^ swk));
                    c0 = __builtin_amdgcn_mfma_f32_16x16x32_bf16(ax, w0, c0, 0, 0, 0);
                    c1 = __builtin_amdgcn_mfma_f32_16x16x32_bf16(ax, w1, c1, 0, 0, 0);
                }
            }

            // F: issue next sub's HBM row-slice prefetch
            if (s < 7) {
                const float* xr = xbase + ((size_t)(s + 1) * 32 + (size_t)(rg * 16 + l15)) * DD + lg4 * 8;
#pragma unroll
                for (int ks = 0; ks < 8; ks++) {
                    pf[2 * ks]     = *(const float4*)(xr + ks * 32);
                    pf[2 * ks + 1] = *(const float4*)(xr + ks * 32 + 4);
                }
            }
            __builtin_amdgcn_sched_barrier(0);

            // G: softmax over k=32, fully in-register
            float a0v[4], a1v[4];
#pragma unroll
            for (int r = 0; r < 4; r++) {
                float m = fmaxf(c0[r], c1[r]);
                m = fmaxf(m, __shfl_xor(m, 1));
                m = fmaxf(m, __shfl_xor(m, 2));
                m = fmaxf(m, __shfl_xor(m, 4));
                m = fmaxf(m, __shfl_xor(m, 8));
                float p0 = __expf(c0[r] - m), p1 = __expf(c1[r] - m);
                float ss = p0 + p1;
                ss += __shfl_xor(ss, 1);
                ss += __shfl_xor(ss, 2);
                ss += __shfl_xor(ss, 4);
                ss += __shfl_xor(ss, 8);
                float inv = 1.0f / ss;
                a0v[r] = p0 * inv; a1v[r] = p1 * inv;
            }
            asr0 += a0v[0] + a0v[1] + a0v[2] + a0v[3];
            asr1 += a1v[0] + a1v[1] + a1v[2] + a1v[3];
            af0 = make_uint4(pk2(a0v[0], a0v[1]), pk2(a0v[2], a0v[3]), 0, 0);
            af1 = make_uint4(pk2(a1v[0], a1v[1]), pk2(a1v[2], a1v[3]), 0, 0);
        }

        // tail aggregation for sub 7
        KWAIT();
#pragma unroll
        for (int dt = 0; dt < 8; dt++) {
            int dl = dt * 16 + l15;
            unsigned sw = ((unsigned)(dl >> 3) & 1u) << 4;
            uint2 blv = *(const uint2*)(xtw + dl * 32 + ((lg4 * 8) ^ sw));
            bf16x8 bv = u4bf(make_uint4(blv.x, blv.y, 0, 0));
            acc0[dt] = __builtin_amdgcn_mfma_f32_16x16x32_bf16(u4bf(af0), bv, acc0[dt], 0, 0, 0);
            acc1[dt] = __builtin_amdgcn_mfma_f32_16x16x32_bf16(u4bf(af1), bv, acc1[dt], 0, 0, 0);
        }
    }   // pass

    // ---- asum: reduce over lg4 groups; dh==0 wave of each pair stores ----
    asr0 += __shfl_xor(asr0, 16);  asr0 += __shfl_xor(asr0, 32);
    asr1 += __shfl_xor(asr1, 16);  asr1 += __shfl_xor(asr1, 32);
    if (dh == 0 && l < 16) {
        float* ap = apart + ((size_t)bid * 2 + rg) * KK;
        ap[l15]      = asr0;
        ap[16 + l15] = asr1;
    }

    // ---- epilogue: cross-pair v reduce via LDS (Wl/xt dead) ----
    __syncthreads();
    float* vb = (float*)lds;           // [32][260] f32
    if (rg == 0) {
#pragma unroll
        for (int dt = 0; dt < 8; dt++) {
            int d = dh * 128 + dt * 16 + l15;
#pragma unroll
            for (int r = 0; r < 4; r++) {
                int k0 = lg4 * 4 + r;
                vb[k0 * 260 + d]        = acc0[dt][r];
                vb[(16 + k0) * 260 + d] = acc1[dt][r];
            }
        }
    }
    __syncthreads();
    if (rg == 1) {
#pragma unroll
        for (int dt = 0; dt < 8; dt++) {
            int d = dh * 128 + dt * 16 + l15;
#pragma unroll
            for (int r = 0; r < 4; r++) {
                int k0 = lg4 * 4 + r;
                vb[k0 * 260 + d]        += acc0[dt][r];
                vb[(16 + k0) * 260 + d] += acc1[dt][r];
            }
        }
    }
    __syncthreads();
    float* vp = vpart + (size_t)bid * KK * DD;
#pragma unroll
    for (int i = 0; i < 8; i++) {
        int f = i * 256 + t;
        int k = f >> 6, c4 = f & 63;
        f32x4 v4 = *(const f32x4*)&vb[k * 260 + c4 * 4];
        *(f32x4*)&vp[(size_t)k * DD + c4 * 4] = v4;
    }
}

// kC: reduce 64 v-partials + 128 asum-partials, subtract a_sum*k_mean, normalize.
__global__ void netvlad_kC(const float* __restrict__ vpart,
                           const float* __restrict__ apart,
                           const float* __restrict__ kmean,
                           float* __restrict__ out) {
    const int bi = blockIdx.x / KK;
    const int k  = blockIdx.x % KK;
    const int t  = threadIdx.x;   // d

    float v = 0.0f;
    for (int j = 0; j < 64; j++)
        v += vpart[(((size_t)bi * 64 + j) * KK + k) * DD + t];

    float asum = 0.0f;
    for (int j = 0; j < 128; j++)
        asum += apart[((size_t)bi * 128 + j) * KK + k];

    v -= asum * kmean[(size_t)k * DD + t];

    float sq = v * v;
    sq += __shfl_xor(sq, 1);  sq += __shfl_xor(sq, 2);  sq += __shfl_xor(sq, 4);
    sq += __shfl_xor(sq, 8);  sq += __shfl_xor(sq, 16); sq += __shfl_xor(sq, 32);
    __shared__ float red[4];
    if ((t & 63) == 0) red[t >> 6] = sq;
    __syncthreads();
    float tot = red[0] + red[1] + red[2] + red[3];

    const float EPS = 1e-12f;
    float invn = 1.0f / fmaxf(sqrtf(tot), EPS);
    const float invK = 0.1767766952966369f;  // 1/sqrt(32): global norm after intra-norm
    out[((size_t)bi * KK + k) * DD + t] = v * invn * invK;
}

extern "C" void kernel_launch(void* const* d_in, const int* in_sizes, int n_in,
                              void* d_out, int out_size, void* d_ws, size_t ws_size,
                              hipStream_t stream) {
    const float* x     = (const float*)d_in[0];
    const float* W     = (const float*)d_in[1];
    const float* bias  = (const float*)d_in[2];
    const float* kmean = (const float*)d_in[3];
    float* out = (float*)d_out;

    // ws carve: vpart (1024*32*256 f32 = 33.55MB) | apart (1024*2*32 f32 = 256KB)
    float* vpart = (float*)d_ws;
    float* apart = vpart + (size_t)1024 * KK * DD;

    hipLaunchKernelGGL(netvlad_k1, dim3(1024), dim3(256), 0, stream,
                       x, W, bias, vpart, apart);
    hipLaunchKernelGGL(netvlad_kC, dim3(BB * KK), dim3(256), 0, stream,
                       vpart, apart, kmean, out);
}

// Round 16
// 134.982 us; speedup vs baseline: 1.3937x; 1.3937x over previous
//
#include <hip/hip_runtime.h>
#include <hip/hip_bf16.h>
#include <math.h>

#define BB 16
#define NN 16384
#define DD 256
#define KK 32

typedef short bf16x8 __attribute__((ext_vector_type(8)));
typedef float f32x4 __attribute__((ext_vector_type(4)));

__device__ inline unsigned pk2(float lo, float hi) {
    __hip_bfloat162 h = __float22bfloat162_rn(make_float2(lo, hi));
    union { __hip_bfloat162 h; unsigned u; } v; v.h = h;
    return v.u;
}
__device__ inline bf16x8 u4bf(uint4 q) {
    union { uint4 u; bf16x8 v; } c; c.u = q; return c.v;
}

// intra-wave LDS drain + scheduler fence (rule #18)
#define KWAIT() do { asm volatile("s_waitcnt lgkmcnt(0)" ::: "memory"); \
                     __builtin_amdgcn_sched_barrier(0); } while (0)
// raw barrier + compiler memory fence (no vmcnt drain: reg loads stay in flight)
#define KBARF() do { asm volatile("s_waitcnt lgkmcnt(0)" ::: "memory"); \
                     __builtin_amdgcn_s_barrier();                      \
                     asm volatile("" ::: "memory");                     \
                     __builtin_amdgcn_sched_barrier(0); } while (0)

// f32x4 read from swizzled xr tile: row n, 16B chunk index c in [0,64):
// byte = n*1024 + ((c ^ (n&7)) << 4). Write side uses the SAME algebra, so the
// pair is correct by construction (r14/r15's global_load_lds deposit model was
// the unverifiable link -> replaced with reg-staged ds_write, HK T14 pattern).
__device__ inline float4 xr_rd4(const char* buf, int n, int chunk) {
    return *(const float4*)(buf + n * 1024 + (((unsigned)(chunk ^ (n & 7))) << 4));
}

// k1: 256 thr = 4 waves, 2 blocks/CU (64KB LDS). Single x-tile buffer + reg
// ping: compute sub s from buf while regs hold sub s+1; after the read-done
// barrier, ds_write regs->buf (swizzled), issue sub s+2 global loads, publish
// with lgkm+barrier. Waves: rg = w>>1 owns rows rg*16..+15 (logits dup in dh
// pair); dh = w&1 owns d-half. acc 64 + staging 32 regs -> no spill at (256,2).
__launch_bounds__(256, 2)
__global__ void netvlad_k1(const float* __restrict__ x,
                           const float* __restrict__ W,
                           const float* __restrict__ bias,
                           float* __restrict__ vpart,
                           float* __restrict__ apart) {
    __shared__ __align__(16) char lds[65536];
    // [0,16384):     Wl bf16, byte = k*512 + (dbyte ^ ((k&7)<<4))
    // [16384,49152): xr buf (32 rows x 1KB f32, swizzled per xr_rd4)
    // [49152,65536): xt per-wave 4KB: dl*32 + (nbyte ^ (((dl>>3)&1)<<4))
    // epilogue: vbuf f32 [32][260] at byte 0

    const int t   = threadIdx.x;
    const int l   = t & 63;
    const int w   = t >> 6;
    const int rg  = w >> 1;            // row-group: rows rg*16..+15 of each sub
    const int dh  = w & 1;             // d-half: [dh*128, dh*128+128)
    const int l15 = l & 15;
    const int lg4 = l >> 4;
    const int rh  = l >> 5;            // agg-src row-half
    const int cl  = l & 31;            // agg-src col slot
    const int bid = blockIdx.x;
    const int b   = bid >> 6;          // batch
    const int blk = bid & 63;          // 256-row chunk

    // ---- stage Wl (bf16, swizzled) once — proven r11 ----
    for (int i = 0; i < 8; i++) {
        int f = i * 256 + t;           // float4 index in [0,2048)
        int k = f >> 6, c4 = f & 63;
        float4 wv = ((const float4*)W)[f];
        int byte = k * 512 + ((c4 * 8) ^ ((k & 7) << 4));
        *(uint2*)(lds + byte) = make_uint2(pk2(wv.x, wv.y), pk2(wv.z, wv.w));
    }
    const float cb0 = bias[l15];
    const float cb1 = bias[16 + l15];

    char* buf = lds + 16384;
    char* xtw = lds + 49152 + w * 4096;

    f32x4 acc0[8], acc1[8];
#pragma unroll
    for (int i = 0; i < 8; i++) { acc0[i] = (f32x4){0,0,0,0}; acc1[i] = (f32x4){0,0,0,0}; }
    float asr0 = 0.f, asr1 = 0.f;

    const float* xbase = x + ((size_t)b * NN + (size_t)blk * 256) * DD;
    // wave w stages rows rw = w*8+i of each 32-row sub; lane l owns bytes [l*16,+16)
    // LDS write byte = rw*1024 + ((l*16) ^ ((rw&7)<<4));  rw&7 == i.

    // prologue: load sub0 -> regs, write to buf, load sub1 -> regs, publish.
    float4 st[8];
#pragma unroll
    for (int i = 0; i < 8; i++)
        st[i] = *(const float4*)((const char*)(xbase + (size_t)(w * 8 + i) * DD) + l * 16);
#pragma unroll
    for (int i = 0; i < 8; i++)
        *(float4*)(buf + (w * 8 + i) * 1024 + ((l * 16) ^ (i << 4))) = st[i];
#pragma unroll
    for (int i = 0; i < 8; i++)
        st[i] = *(const float4*)((const char*)(xbase + (size_t)(32 + w * 8 + i) * DD) + l * 16);
    KBARF();                           // buf(sub0) published; Wl ready too

#pragma unroll 1
    for (int s = 0; s < 8; s++) {
        // 3: agg-source col reads from xr
        float4 ca[8];
#pragma unroll
        for (int i = 0; i < 8; i++)
            ca[i] = xr_rd4(buf, rg * 16 + rh * 8 + i, dh * 32 + cl);

        // 4: logits mfma (A = x rows read from xr, B = W^T from Wl) — r11 numerics
        f32x4 c0 = (f32x4){cb0, cb0, cb0, cb0};
        f32x4 c1 = (f32x4){cb1, cb1, cb1, cb1};
        {
            const int n = rg * 16 + l15;
            const unsigned swk = ((unsigned)(l15 & 7)) << 4;
#pragma unroll
            for (int ks = 0; ks < 8; ks++) {
                float4 lo = xr_rd4(buf, n, ks * 8 + lg4 * 2 + 0);
                float4 hi = xr_rd4(buf, n, ks * 8 + lg4 * 2 + 1);
                uint4 xq;
                xq.x = pk2(lo.x, lo.y); xq.y = pk2(lo.z, lo.w);
                xq.z = pk2(hi.x, hi.y); xq.w = pk2(hi.z, hi.w);
                bf16x8 ax = u4bf(xq);
                bf16x8 w0 = *(const bf16x8*)(lds + l15 * 512        + (((unsigned)(ks * 64 + lg4 * 16)) ^ swk));
                bf16x8 w1 = *(const bf16x8*)(lds + (16 + l15) * 512 + (((unsigned)(ks * 64 + lg4 * 16)) ^ swk));
                c0 = __builtin_amdgcn_mfma_f32_16x16x32_bf16(ax, w0, c0, 0, 0, 0);
                c1 = __builtin_amdgcn_mfma_f32_16x16x32_bf16(ax, w1, c1, 0, 0, 0);
            }
        }

        // 5: stage wave-private x^T quarter-tile (r11 C/D exact, source = ca)
#pragma unroll
        for (int e = 0; e < 4; e++) {
            int dl = cl * 4 + e;
            unsigned sw = ((unsigned)(dl >> 3) & 1u) << 4;
            uint4 q;
            q.x = pk2((e == 0 ? ca[0].x : e == 1 ? ca[0].y : e == 2 ? ca[0].z : ca[0].w),
                      (e == 0 ? ca[1].x : e == 1 ? ca[1].y : e == 2 ? ca[1].z : ca[1].w));
            q.y = pk2((e == 0 ? ca[2].x : e == 1 ? ca[2].y : e == 2 ? ca[2].z : ca[2].w),
                      (e == 0 ? ca[3].x : e == 1 ? ca[3].y : e == 2 ? ca[3].z : ca[3].w));
            q.z = pk2((e == 0 ? ca[4].x : e == 1 ? ca[4].y : e == 2 ? ca[4].z : ca[4].w),
                      (e == 0 ? ca[5].x : e == 1 ? ca[5].y : e == 2 ? ca[5].z : ca[5].w));
            q.w = pk2((e == 0 ? ca[6].x : e == 1 ? ca[6].y : e == 2 ? ca[6].z : ca[6].w),
                      (e == 0 ? ca[7].x : e == 1 ? ca[7].y : e == 2 ? ca[7].z : ca[7].w));
            *(uint4*)(xtw + dl * 32 + (((unsigned)(rh * 16)) ^ sw)) = q;
        }

        // 6: softmax over k=32, fully in-register — r11 exact
        float a0v[4], a1v[4];
#pragma unroll
        for (int r = 0; r < 4; r++) {
            float m = fmaxf(c0[r], c1[r]);
            m = fmaxf(m, __shfl_xor(m, 1));
            m = fmaxf(m, __shfl_xor(m, 2));
            m = fmaxf(m, __shfl_xor(m, 4));
            m = fmaxf(m, __shfl_xor(m, 8));
            float p0 = __expf(c0[r] - m), p1 = __expf(c1[r] - m);
            float ss = p0 + p1;
            ss += __shfl_xor(ss, 1);
            ss += __shfl_xor(ss, 2);
            ss += __shfl_xor(ss, 4);
            ss += __shfl_xor(ss, 8);
            float inv = 1.0f / ss;
            a0v[r] = p0 * inv; a1v[r] = p1 * inv;
        }
        asr0 += a0v[0] + a0v[1] + a0v[2] + a0v[3];
        asr1 += a1v[0] + a1v[1] + a1v[2] + a1v[3];
        uint4 af0 = make_uint4(pk2(a0v[0], a0v[1]), pk2(a0v[2], a0v[3]), 0, 0);
        uint4 af1 = make_uint4(pk2(a1v[0], a1v[1]), pk2(a1v[2], a1v[3]), 0, 0);

        // 7: drain LDS (xt writes visible cross-lane; buf reads retired)
        KWAIT();

        // 8: aggregation mfma — r11 exact addressing
#pragma unroll
        for (int dt = 0; dt < 8; dt++) {
            int dl = dt * 16 + l15;
            unsigned sw = ((unsigned)(dl >> 3) & 1u) << 4;
            uint2 blv = *(const uint2*)(xtw + dl * 32 + ((lg4 * 8) ^ sw));
            bf16x8 bv = u4bf(make_uint4(blv.x, blv.y, 0, 0));
            acc0[dt] = __builtin_amdgcn_mfma_f32_16x16x32_bf16(u4bf(af0), bv, acc0[dt], 0, 0, 0);
            acc1[dt] = __builtin_amdgcn_mfma_f32_16x16x32_bf16(u4bf(af1), bv, acc1[dt], 0, 0, 0);
        }
        KBARF();                        // all waves done reading buf (sub s)

        // 9: publish sub s+1 (ds_write staged regs), issue sub s+2 loads
        if (s < 7) {
#pragma unroll
            for (int i = 0; i < 8; i++)
                *(float4*)(buf + (w * 8 + i) * 1024 + ((l * 16) ^ (i << 4))) = st[i];
            if (s < 6) {
                const float* xn = xbase + (size_t)(s + 2) * 32 * DD;
#pragma unroll
                for (int i = 0; i < 8; i++)
                    st[i] = *(const float4*)((const char*)(xn + (size_t)(w * 8 + i) * DD) + l * 16);
            }
            KBARF();                    // buf(sub s+1) published
        }
    }

    // ---- asum: reduce over lg4 groups; dh==0 wave of each pair stores ----
    asr0 += __shfl_xor(asr0, 16);  asr0 += __shfl_xor(asr0, 32);
    asr1 += __shfl_xor(asr1, 16);  asr1 += __shfl_xor(asr1, 32);
    if (dh == 0 && l < 16) {
        float* ap = apart + ((size_t)bid * 2 + rg) * KK;
        ap[l15]      = asr0;
        ap[16 + l15] = asr1;
    }

    // ---- epilogue: cross-pair v reduce via LDS (Wl/buf/xt dead) — r11 exact ----
    __syncthreads();
    float* vb = (float*)lds;           // [32][260] f32
    if (rg == 0) {
#pragma unroll
        for (int dt = 0; dt < 8; dt++) {
            int d = dh * 128 + dt * 16 + l15;
#pragma unroll
            for (int r = 0; r < 4; r++) {
                int k0 = lg4 * 4 + r;
                vb[k0 * 260 + d]        = acc0[dt][r];
                vb[(16 + k0) * 260 + d] = acc1[dt][r];
            }
        }
    }
    __syncthreads();
    if (rg == 1) {
#pragma unroll
        for (int dt = 0; dt < 8; dt++) {
            int d = dh * 128 + dt * 16 + l15;
#pragma unroll
            for (int r = 0; r < 4; r++) {
                int k0 = lg4 * 4 + r;
                vb[k0 * 260 + d]        += acc0[dt][r];
                vb[(16 + k0) * 260 + d] += acc1[dt][r];
            }
        }
    }
    __syncthreads();
    float* vp = vpart + (size_t)bid * KK * DD;
#pragma unroll
    for (int i = 0; i < 8; i++) {
        int f = i * 256 + t;
        int k = f >> 6, c4 = f & 63;
        f32x4 v4 = *(const f32x4*)&vb[k * 260 + c4 * 4];
        *(f32x4*)&vp[(size_t)k * DD + c4 * 4] = v4;
    }
}

// kC: reduce 64 v-partials + 128 asum-partials, subtract a_sum*k_mean, normalize.
__global__ void netvlad_kC(const float* __restrict__ vpart,
                           const float* __restrict__ apart,
                           const float* __restrict__ kmean,
                           float* __restrict__ out) {
    const int bi = blockIdx.x / KK;
    const int k  = blockIdx.x % KK;
    const int t  = threadIdx.x;   // d

    float v = 0.0f;
    for (int j = 0; j < 64; j++)
        v += vpart[(((size_t)bi * 64 + j) * KK + k) * DD + t];

    float asum = 0.0f;
    for (int j = 0; j < 128; j++)
        asum += apart[((size_t)bi * 128 + j) * KK + k];

    v -= asum * kmean[(size_t)k * DD + t];

    float sq = v * v;
    sq += __shfl_xor(sq, 1);  sq += __shfl_xor(sq, 2);  sq += __shfl_xor(sq, 4);
    sq += __shfl_xor(sq, 8);  sq += __shfl_xor(sq, 16); sq += __shfl_xor(sq, 32);
    __shared__ float red[4];
    if ((t & 63) == 0) red[t >> 6] = sq;
    __syncthreads();
    float tot = red[0] + red[1] + red[2] + red[3];

    const float EPS = 1e-12f;
    float invn = 1.0f / fmaxf(sqrtf(tot), EPS);
    const float invK = 0.1767766952966369f;  // 1/sqrt(32): global norm after intra-norm
    out[((size_t)bi * KK + k) * DD + t] = v * invn * invK;
}

extern "C" void kernel_launch(void* const* d_in, const int* in_sizes, int n_in,
                              void* d_out, int out_size, void* d_ws, size_t ws_size,
                              hipStream_t stream) {
    const float* x     = (const float*)d_in[0];
    const float* W     = (const float*)d_in[1];
    const float* bias  = (const float*)d_in[2];
    const float* kmean = (const float*)d_in[3];
    float* out = (float*)d_out;

    // ws carve: vpart (1024*32*256 f32 = 33.55MB) | apart (1024*2*32 f32 = 256KB)
    float* vpart = (float*)d_ws;
    float* apart = vpart + (size_t)1024 * KK * DD;

    hipLaunchKernelGGL(netvlad_k1, dim3(1024), dim3(256), 0, stream,
                       x, W, bias, vpart, apart);
    hipLaunchKernelGGL(netvlad_kC, dim3(BB * KK), dim3(256), 0, stream,
                       vpart, apart, kmean, out);
}

// Round 17
// 106.348 us; speedup vs baseline: 1.7690x; 1.2692x over previous
//
#include <hip/hip_runtime.h>
#include <hip/hip_bf16.h>
#include <math.h>

#define BB 16
#define NN 16384
#define DD 256
#define KK 32

typedef short bf16x8 __attribute__((ext_vector_type(8)));
typedef float f32x4 __attribute__((ext_vector_type(4)));

__device__ inline unsigned pk2(float lo, float hi) {
    __hip_bfloat162 h = __float22bfloat162_rn(make_float2(lo, hi));
    union { __hip_bfloat162 h; unsigned u; } v; v.h = h;
    return v.u;
}
__device__ inline bf16x8 u4bf(uint4 q) {
    union { uint4 u; bf16x8 v; } c; c.u = q; return c.v;
}

// intra-wave LDS drain + scheduler fence (rule #18)
#define KWAIT() do { asm volatile("s_waitcnt lgkmcnt(0)" ::: "memory"); \
                     __builtin_amdgcn_sched_barrier(0); } while (0)

// compile-time float4 component select
#define CAE(vv, e) ((e) == 0 ? (vv).x : (e) == 1 ? (vv).y : (e) == 2 ? (vv).z : (vv).w)

// r10 (best: 103.2us) + two micro-fixes:
//  (1) ALL 16 ca col-loads issued in step A -> deferred-agg MFMA covers both
//      batches' L2 latency (r10 exposed the second 8 inside C/D).
//  (2) s_setprio(1) around MFMA clusters (independent-wave regime, m191).
// bounds(256,1): 512 unified regs/wave, demand ~296 -> zero spill (r9 lesson).
__launch_bounds__(256, 1)
__global__ void netvlad_k1(const float* __restrict__ x,
                           const float* __restrict__ W,
                           const float* __restrict__ bias,
                           float* __restrict__ vpart,
                           float* __restrict__ apart) {
    __shared__ __align__(16) char lds[49152];
    // [0,16384): Wl bf16, byte = k*512 + (dbyte ^ ((k&7)<<4))
    // [16384,49152): xt per-wave 8KB: d*32 + (nbyte ^ (((d>>3)&1)<<4))
    // epilogue: vbuf f32 [32][260] at byte 0

    const int t   = threadIdx.x;
    const int l   = t & 63;
    const int w   = t >> 6;
    const int l15 = l & 15;
    const int lg4 = l >> 4;
    const int bid = blockIdx.x;
    const int b   = bid >> 5;
    const int blk = bid & 31;

    // ---- stage Wl (bf16, swizzled) once ----
    for (int i = 0; i < 8; i++) {
        int f = i * 256 + t;             // float4 index in [0,2048)
        int k = f >> 6, c4 = f & 63;
        float4 wv = ((const float4*)W)[f];
        int byte = k * 512 + ((c4 * 8) ^ ((k & 7) << 4));
        *(uint2*)(lds + byte) = make_uint2(pk2(wv.x, wv.y), pk2(wv.z, wv.w));
    }
    const float cb0 = bias[l15];
    const float cb1 = bias[16 + l15];
    __syncthreads();                     // once; Wl read-only afterwards

    char* xtw = lds + 16384 + w * 8192;

    f32x4 acc0[16], acc1[16];
#pragma unroll
    for (int i = 0; i < 16; i++) { acc0[i] = (f32x4){0,0,0,0}; acc1[i] = (f32x4){0,0,0,0}; }
    float asr0 = 0.f, asr1 = 0.f;

    const float* xbase = x + ((size_t)b * NN + (size_t)blk * 512) * DD;

    // prologue: prefetch sub-0 row-slices
    float4 pf[16];
    {
        const float* xr = xbase + (size_t)(w * 16 + l15) * DD + lg4 * 8;
#pragma unroll
        for (int ks = 0; ks < 8; ks++) {
            pf[2 * ks]     = *(const float4*)(xr + ks * 32);
            pf[2 * ks + 1] = *(const float4*)(xr + ks * 32 + 4);
        }
    }

    uint4 af0 = make_uint4(0, 0, 0, 0), af1 = make_uint4(0, 0, 0, 0);

#pragma unroll 1
    for (int s = 0; s < 8; s++) {
        const float* xsub = xbase + ((size_t)s * 64 + (size_t)w * 16) * DD;

        // A: issue ALL 16 ca col-loads (L2-hot; latency covered by agg B below)
        float4 ca[16];
#pragma unroll
        for (int i = 0; i < 16; i++)
            ca[i] = *(const float4*)(xsub + (size_t)i * DD + l * 4);

        // B: deferred aggregation for sub s-1 (covers ca latency)
        if (s > 0) {
            KWAIT();
            __builtin_amdgcn_s_setprio(1);
#pragma unroll
            for (int dt = 0; dt < 16; dt++) {
                int d = dt * 16 + l15;
                unsigned sw = ((unsigned)(d >> 3) & 1u) << 4;
                uint2 bl = *(const uint2*)(xtw + d * 32 + ((lg4 * 8) ^ sw));
                bf16x8 bv = u4bf(make_uint4(bl.x, bl.y, 0, 0));
                acc0[dt] = __builtin_amdgcn_mfma_f32_16x16x32_bf16(u4bf(af0), bv, acc0[dt], 0, 0, 0);
                acc1[dt] = __builtin_amdgcn_mfma_f32_16x16x32_bf16(u4bf(af1), bv, acc1[dt], 0, 0, 0);
            }
            __builtin_amdgcn_s_setprio(0);
        }

        // C/D: stage wave-private x^T tile (two 8-row halves, register transpose)
#pragma unroll
        for (int half = 0; half < 2; half++) {
#pragma unroll
            for (int e = 0; e < 4; e++) {
                int d = 4 * l + e;
                unsigned sw = ((unsigned)(d >> 3) & 1u) << 4;
                uint4 q;
                q.x = pk2(CAE(ca[half * 8 + 0], e), CAE(ca[half * 8 + 1], e));
                q.y = pk2(CAE(ca[half * 8 + 2], e), CAE(ca[half * 8 + 3], e));
                q.z = pk2(CAE(ca[half * 8 + 4], e), CAE(ca[half * 8 + 5], e));
                q.w = pk2(CAE(ca[half * 8 + 6], e), CAE(ca[half * 8 + 7], e));
                *(uint4*)(xtw + d * 32 + (((unsigned)(half * 16)) ^ sw)) = q;
            }
        }

        // E: logits mfma(A = x row-frags from pf, B = W^T from Wl)
        f32x4 c0 = (f32x4){cb0, cb0, cb0, cb0};
        f32x4 c1 = (f32x4){cb1, cb1, cb1, cb1};
        {
            const unsigned swk = ((unsigned)(l15 & 7)) << 4;
            __builtin_amdgcn_s_setprio(1);
#pragma unroll
            for (int ks = 0; ks < 8; ks++) {
                uint4 xq;
                xq.x = pk2(pf[2 * ks].x,     pf[2 * ks].y);
                xq.y = pk2(pf[2 * ks].z,     pf[2 * ks].w);
                xq.z = pk2(pf[2 * ks + 1].x, pf[2 * ks + 1].y);
                xq.w = pk2(pf[2 * ks + 1].z, pf[2 * ks + 1].w);
                bf16x8 ax = u4bf(xq);
                bf16x8 w0 = *(const bf16x8*)(lds + l15 * 512        + (((unsigned)(ks * 64 + lg4 * 16)) ^ swk));
                bf16x8 w1 = *(const bf16x8*)(lds + (16 + l15) * 512 + (((unsigned)(ks * 64 + lg4 * 16)) ^ swk));
                c0 = __builtin_amdgcn_mfma_f32_16x16x32_bf16(ax, w0, c0, 0, 0, 0);
                c1 = __builtin_amdgcn_mfma_f32_16x16x32_bf16(ax, w1, c1, 0, 0, 0);
            }
            __builtin_amdgcn_s_setprio(0);
        }

        // F: issue next sub's HBM row-slice prefetch
        if (s < 7) {
            const float* xr = xbase + ((size_t)(s + 1) * 64 + (size_t)(w * 16 + l15)) * DD + lg4 * 8;
#pragma unroll
            for (int ks = 0; ks < 8; ks++) {
                pf[2 * ks]     = *(const float4*)(xr + ks * 32);
                pf[2 * ks + 1] = *(const float4*)(xr + ks * 32 + 4);
            }
        }
        __builtin_amdgcn_sched_barrier(0);

        // G: softmax over k=32 (16 lanes x 2 tiles), fully in-register
        float a0v[4], a1v[4];
#pragma unroll
        for (int r = 0; r < 4; r++) {
            float m = fmaxf(c0[r], c1[r]);
            m = fmaxf(m, __shfl_xor(m, 1));
            m = fmaxf(m, __shfl_xor(m, 2));
            m = fmaxf(m, __shfl_xor(m, 4));
            m = fmaxf(m, __shfl_xor(m, 8));
            float p0 = __expf(c0[r] - m), p1 = __expf(c1[r] - m);
            float ss = p0 + p1;
            ss += __shfl_xor(ss, 1);
            ss += __shfl_xor(ss, 2);
            ss += __shfl_xor(ss, 4);
            ss += __shfl_xor(ss, 8);
            float inv = 1.0f / ss;
            a0v[r] = p0 * inv; a1v[r] = p1 * inv;
        }
        asr0 += a0v[0] + a0v[1] + a0v[2] + a0v[3];
        asr1 += a1v[0] + a1v[1] + a1v[2] + a1v[3];
        af0 = make_uint4(pk2(a0v[0], a0v[1]), pk2(a0v[2], a0v[3]), 0, 0);
        af1 = make_uint4(pk2(a1v[0], a1v[1]), pk2(a1v[2], a1v[3]), 0, 0);
    }

    // tail aggregation for sub 7
    KWAIT();
#pragma unroll
    for (int dt = 0; dt < 16; dt++) {
        int d = dt * 16 + l15;
        unsigned sw = ((unsigned)(d >> 3) & 1u) << 4;
        uint2 bl = *(const uint2*)(xtw + d * 32 + ((lg4 * 8) ^ sw));
        bf16x8 bv = u4bf(make_uint4(bl.x, bl.y, 0, 0));
        acc0[dt] = __builtin_amdgcn_mfma_f32_16x16x32_bf16(u4bf(af0), bv, acc0[dt], 0, 0, 0);
        acc1[dt] = __builtin_amdgcn_mfma_f32_16x16x32_bf16(u4bf(af1), bv, acc1[dt], 0, 0, 0);
    }

    // ---- asum: reduce over lg4 groups; per-wave global partials ----
    asr0 += __shfl_xor(asr0, 16);  asr0 += __shfl_xor(asr0, 32);
    asr1 += __shfl_xor(asr1, 16);  asr1 += __shfl_xor(asr1, 32);
    if (l < 16) {
        float* ap = apart + ((size_t)bid * 4 + w) * KK;
        ap[l15]      = asr0;
        ap[16 + l15] = asr1;
    }

    // ---- epilogue: cross-wave v reduce via LDS (Wl/xt dead) ----
    __syncthreads();
    float* vb = (float*)lds;             // [32][260] f32
    for (int ww = 0; ww < 4; ww++) {
        if (w == ww) {
#pragma unroll
            for (int dt = 0; dt < 16; dt++) {
                int d = dt * 16 + l15;
#pragma unroll
                for (int r = 0; r < 4; r++) {
                    int k0 = lg4 * 4 + r;
                    if (ww == 0) {
                        vb[k0 * 260 + d]        = acc0[dt][r];
                        vb[(16 + k0) * 260 + d] = acc1[dt][r];
                    } else {
                        vb[k0 * 260 + d]        += acc0[dt][r];
                        vb[(16 + k0) * 260 + d] += acc1[dt][r];
                    }
                }
            }
        }
        __syncthreads();
    }
    float* vp = vpart + (size_t)bid * KK * DD;
#pragma unroll
    for (int i = 0; i < 8; i++) {
        int f = i * 256 + t;
        int k = f >> 6, c4 = f & 63;
        f32x4 v4 = *(const f32x4*)&vb[k * 260 + c4 * 4];
        *(f32x4*)&vp[(size_t)k * DD + c4 * 4] = v4;
    }
}

// kC: reduce 32 v-partials + 128 asum-partials, subtract a_sum*k_mean, normalize.
__global__ void netvlad_kC(const float* __restrict__ vpart,
                           const float* __restrict__ apart,
                           const float* __restrict__ kmean,
                           float* __restrict__ out) {
    const int bi = blockIdx.x / KK;
    const int k  = blockIdx.x % KK;
    const int t  = threadIdx.x;   // d

    float v = 0.0f;
    for (int j = 0; j < 32; j++)
        v += vpart[(((size_t)bi * 32 + j) * KK + k) * DD + t];

    float asum = 0.0f;
    for (int j = 0; j < 128; j++)
        asum += apart[((size_t)bi * 128 + j) * KK + k];

    v -= asum * kmean[(size_t)k * DD + t];

    float sq = v * v;
    sq += __shfl_xor(sq, 1);  sq += __shfl_xor(sq, 2);  sq += __shfl_xor(sq, 4);
    sq += __shfl_xor(sq, 8);  sq += __shfl_xor(sq, 16); sq += __shfl_xor(sq, 32);
    __shared__ float red[4];
    if ((t & 63) == 0) red[t >> 6] = sq;
    __syncthreads();
    float tot = red[0] + red[1] + red[2] + red[3];

    const float EPS = 1e-12f;
    float invn = 1.0f / fmaxf(sqrtf(tot), EPS);
    const float invK = 0.1767766952966369f;  // 1/sqrt(32): global norm after intra-norm
    out[((size_t)bi * KK + k) * DD + t] = v * invn * invK;
}

extern "C" void kernel_launch(void* const* d_in, const int* in_sizes, int n_in,
                              void* d_out, int out_size, void* d_ws, size_t ws_size,
                              hipStream_t stream) {
    const float* x     = (const float*)d_in[0];
    const float* W     = (const float*)d_in[1];
    const float* bias  = (const float*)d_in[2];
    const float* kmean = (const float*)d_in[3];
    float* out = (float*)d_out;

    // ws carve: vpart (512*32*256 f32 = 16.8MB) | apart (2048*32 f32 = 256KB)
    float* vpart = (float*)d_ws;
    float* apart = vpart + (size_t)512 * KK * DD;

    hipLaunchKernelGGL(netvlad_k1, dim3(512), dim3(256), 0, stream,
                       x, W, bias, vpart, apart);
    hipLaunchKernelGGL(netvlad_kC, dim3(BB * KK), dim3(256), 0, stream,
                       vpart, apart, kmean, out);
}

// Round 18
// 98.808 us; speedup vs baseline: 1.9040x; 1.0763x over previous
//
#include <hip/hip_runtime.h>
#include <hip/hip_bf16.h>
#include <math.h>

#define BB 16
#define NN 16384
#define DD 256
#define KK 32

typedef short bf16x8 __attribute__((ext_vector_type(8)));
typedef float f32x4 __attribute__((ext_vector_type(4)));

__device__ inline unsigned pk2(float lo, float hi) {
    __hip_bfloat162 h = __float22bfloat162_rn(make_float2(lo, hi));
    union { __hip_bfloat162 h; unsigned u; } v; v.h = h;
    return v.u;
}
__device__ inline bf16x8 u4bf(uint4 q) {
    union { uint4 u; bf16x8 v; } c; c.u = q; return c.v;
}

// compile-time float4 component select
#define CAE(vv, e) ((e) == 0 ? (vv).x : (e) == 1 ? (vv).y : (e) == 2 ? (vv).z : (vv).w)

// r10 (best: 103.2us) with ALL in-loop fences removed (KWAIT / sched_barrier /
// setprio). Rationale: xt is wave-private; same-wave DS ops execute in-order
// (lgkm out-of-order is SMEM-only), and the compiler preserves program order
// for potentially-aliasing LDS ops while auto-inserting fine-grained lgkmcnt
// waits for its own ds_read results. At 1 wave/SIMD, cross-phase ILP is the
// ONLY latency hiding — the fences were forcing phase-serial execution.
// bounds(256,1): 512 unified regs/wave, demand ~296 -> zero spill (r9 lesson).
__launch_bounds__(256, 1)
__global__ void netvlad_k1(const float* __restrict__ x,
                           const float* __restrict__ W,
                           const float* __restrict__ bias,
                           float* __restrict__ vpart,
                           float* __restrict__ apart) {
    __shared__ __align__(16) char lds[49152];
    // [0,16384): Wl bf16, byte = k*512 + (dbyte ^ ((k&7)<<4))
    // [16384,49152): xt per-wave 8KB: d*32 + (nbyte ^ (((d>>3)&1)<<4))
    // epilogue: vbuf f32 [32][260] at byte 0

    const int t   = threadIdx.x;
    const int l   = t & 63;
    const int w   = t >> 6;
    const int l15 = l & 15;
    const int lg4 = l >> 4;
    const int bid = blockIdx.x;
    const int b   = bid >> 5;
    const int blk = bid & 31;

    // ---- stage Wl (bf16, swizzled) once ----
    for (int i = 0; i < 8; i++) {
        int f = i * 256 + t;             // float4 index in [0,2048)
        int k = f >> 6, c4 = f & 63;
        float4 wv = ((const float4*)W)[f];
        int byte = k * 512 + ((c4 * 8) ^ ((k & 7) << 4));
        *(uint2*)(lds + byte) = make_uint2(pk2(wv.x, wv.y), pk2(wv.z, wv.w));
    }
    const float cb0 = bias[l15];
    const float cb1 = bias[16 + l15];
    __syncthreads();                     // once; Wl read-only afterwards

    char* xtw = lds + 16384 + w * 8192;

    f32x4 acc0[16], acc1[16];
#pragma unroll
    for (int i = 0; i < 16; i++) { acc0[i] = (f32x4){0,0,0,0}; acc1[i] = (f32x4){0,0,0,0}; }
    float asr0 = 0.f, asr1 = 0.f;

    const float* xbase = x + ((size_t)b * NN + (size_t)blk * 512) * DD;

    // prologue: prefetch sub-0 row-slices: pf[2ks+h] = x[w*16+l15][ks*32+lg4*8+h*4..]
    float4 pf[16];
    {
        const float* xr = xbase + (size_t)(w * 16 + l15) * DD + lg4 * 8;
#pragma unroll
        for (int ks = 0; ks < 8; ks++) {
            pf[2 * ks]     = *(const float4*)(xr + ks * 32);
            pf[2 * ks + 1] = *(const float4*)(xr + ks * 32 + 4);
        }
    }

    uint4 af0 = make_uint4(0, 0, 0, 0), af1 = make_uint4(0, 0, 0, 0);

#pragma unroll 1
    for (int s = 0; s < 8; s++) {
        const float* xsub = xbase + ((size_t)s * 64 + (size_t)w * 16) * DD;

        // A: issue ca col-loads rows 0-7 (L2-hot: pf stream fetched these lines a sub ago)
        float4 ca[8];
#pragma unroll
        for (int i = 0; i < 8; i++)
            ca[i] = *(const float4*)(xsub + (size_t)i * DD + l * 4);

        // B: deferred aggregation for sub s-1 (covers ca latency).
        // Same-wave DS in-order: xt writes from C/D of sub s-1 are visible.
        if (s > 0) {
#pragma unroll
            for (int dt = 0; dt < 16; dt++) {
                int d = dt * 16 + l15;
                unsigned sw = ((unsigned)(d >> 3) & 1u) << 4;
                uint2 bl = *(const uint2*)(xtw + d * 32 + ((lg4 * 8) ^ sw));
                bf16x8 bv = u4bf(make_uint4(bl.x, bl.y, 0, 0));
                acc0[dt] = __builtin_amdgcn_mfma_f32_16x16x32_bf16(u4bf(af0), bv, acc0[dt], 0, 0, 0);
                acc1[dt] = __builtin_amdgcn_mfma_f32_16x16x32_bf16(u4bf(af1), bv, acc1[dt], 0, 0, 0);
            }
        }

        // C/D: stage wave-private x^T tile (two 8-row halves, register transpose)
#pragma unroll
        for (int half = 0; half < 2; half++) {
            if (half == 1) {
#pragma unroll
                for (int i = 0; i < 8; i++)
                    ca[i] = *(const float4*)(xsub + (size_t)(8 + i) * DD + l * 4);
            }
#pragma unroll
            for (int e = 0; e < 4; e++) {
                int d = 4 * l + e;
                unsigned sw = ((unsigned)(d >> 3) & 1u) << 4;
                uint4 q;
                q.x = pk2(CAE(ca[0], e), CAE(ca[1], e));
                q.y = pk2(CAE(ca[2], e), CAE(ca[3], e));
                q.z = pk2(CAE(ca[4], e), CAE(ca[5], e));
                q.w = pk2(CAE(ca[6], e), CAE(ca[7], e));
                *(uint4*)(xtw + d * 32 + (((unsigned)(half * 16)) ^ sw)) = q;
            }
        }

        // E: logits mfma(A = x row-frags from pf, B = W^T from Wl)
        f32x4 c0 = (f32x4){cb0, cb0, cb0, cb0};
        f32x4 c1 = (f32x4){cb1, cb1, cb1, cb1};
        {
            const unsigned swk = ((unsigned)(l15 & 7)) << 4;
#pragma unroll
            for (int ks = 0; ks < 8; ks++) {
                uint4 xq;
                xq.x = pk2(pf[2 * ks].x,     pf[2 * ks].y);
                xq.y = pk2(pf[2 * ks].z,     pf[2 * ks].w);
                xq.z = pk2(pf[2 * ks + 1].x, pf[2 * ks + 1].y);
                xq.w = pk2(pf[2 * ks + 1].z, pf[2 * ks + 1].w);
                bf16x8 ax = u4bf(xq);
                bf16x8 w0 = *(const bf16x8*)(lds + l15 * 512        + (((unsigned)(ks * 64 + lg4 * 16)) ^ swk));
                bf16x8 w1 = *(const bf16x8*)(lds + (16 + l15) * 512 + (((unsigned)(ks * 64 + lg4 * 16)) ^ swk));
                c0 = __builtin_amdgcn_mfma_f32_16x16x32_bf16(ax, w0, c0, 0, 0, 0);
                c1 = __builtin_amdgcn_mfma_f32_16x16x32_bf16(ax, w1, c1, 0, 0, 0);
            }
        }

        // F: issue next sub's HBM row-slice prefetch (in flight across softmax+agg)
        if (s < 7) {
            const float* xr = xbase + ((size_t)(s + 1) * 64 + (size_t)(w * 16 + l15)) * DD + lg4 * 8;
#pragma unroll
            for (int ks = 0; ks < 8; ks++) {
                pf[2 * ks]     = *(const float4*)(xr + ks * 32);
                pf[2 * ks + 1] = *(const float4*)(xr + ks * 32 + 4);
            }
        }

        // G: softmax over k=32 (16 lanes x 2 tiles), fully in-register
        float a0v[4], a1v[4];
#pragma unroll
        for (int r = 0; r < 4; r++) {
            float m = fmaxf(c0[r], c1[r]);
            m = fmaxf(m, __shfl_xor(m, 1));
            m = fmaxf(m, __shfl_xor(m, 2));
            m = fmaxf(m, __shfl_xor(m, 4));
            m = fmaxf(m, __shfl_xor(m, 8));
            float p0 = __expf(c0[r] - m), p1 = __expf(c1[r] - m);
            float ss = p0 + p1;
            ss += __shfl_xor(ss, 1);
            ss += __shfl_xor(ss, 2);
            ss += __shfl_xor(ss, 4);
            ss += __shfl_xor(ss, 8);
            float inv = 1.0f / ss;
            a0v[r] = p0 * inv; a1v[r] = p1 * inv;
        }
        asr0 += a0v[0] + a0v[1] + a0v[2] + a0v[3];
        asr1 += a1v[0] + a1v[1] + a1v[2] + a1v[3];
        af0 = make_uint4(pk2(a0v[0], a0v[1]), pk2(a0v[2], a0v[3]), 0, 0);
        af1 = make_uint4(pk2(a1v[0], a1v[1]), pk2(a1v[2], a1v[3]), 0, 0);
    }

    // tail aggregation for sub 7 (same-wave DS in-order guarantees xt visible)
#pragma unroll
    for (int dt = 0; dt < 16; dt++) {
        int d = dt * 16 + l15;
        unsigned sw = ((unsigned)(d >> 3) & 1u) << 4;
        uint2 bl = *(const uint2*)(xtw + d * 32 + ((lg4 * 8) ^ sw));
        bf16x8 bv = u4bf(make_uint4(bl.x, bl.y, 0, 0));
        acc0[dt] = __builtin_amdgcn_mfma_f32_16x16x32_bf16(u4bf(af0), bv, acc0[dt], 0, 0, 0);
        acc1[dt] = __builtin_amdgcn_mfma_f32_16x16x32_bf16(u4bf(af1), bv, acc1[dt], 0, 0, 0);
    }

    // ---- asum: reduce over lg4 groups; per-wave global partials ----
    asr0 += __shfl_xor(asr0, 16);  asr0 += __shfl_xor(asr0, 32);
    asr1 += __shfl_xor(asr1, 16);  asr1 += __shfl_xor(asr1, 32);
    if (l < 16) {
        float* ap = apart + ((size_t)bid * 4 + w) * KK;
        ap[l15]      = asr0;
        ap[16 + l15] = asr1;
    }

    // ---- epilogue: cross-wave v reduce via LDS (Wl/xt dead) ----
    __syncthreads();
    float* vb = (float*)lds;             // [32][260] f32
    for (int ww = 0; ww < 4; ww++) {
        if (w == ww) {
#pragma unroll
            for (int dt = 0; dt < 16; dt++) {
                int d = dt * 16 + l15;
#pragma unroll
                for (int r = 0; r < 4; r++) {
                    int k0 = lg4 * 4 + r;
                    if (ww == 0) {
                        vb[k0 * 260 + d]        = acc0[dt][r];
                        vb[(16 + k0) * 260 + d] = acc1[dt][r];
                    } else {
                        vb[k0 * 260 + d]        += acc0[dt][r];
                        vb[(16 + k0) * 260 + d] += acc1[dt][r];
                    }
                }
            }
        }
        __syncthreads();
    }
    float* vp = vpart + (size_t)bid * KK * DD;
#pragma unroll
    for (int i = 0; i < 8; i++) {
        int f = i * 256 + t;
        int k = f >> 6, c4 = f & 63;
        f32x4 v4 = *(const f32x4*)&vb[k * 260 + c4 * 4];
        *(f32x4*)&vp[(size_t)k * DD + c4 * 4] = v4;
    }
}

// kC: reduce 32 v-partials + 128 asum-partials, subtract a_sum*k_mean, normalize.
__global__ void netvlad_kC(const float* __restrict__ vpart,
                           const float* __restrict__ apart,
                           const float* __restrict__ kmean,
                           float* __restrict__ out) {
    const int bi = blockIdx.x / KK;
    const int k  = blockIdx.x % KK;
    const int t  = threadIdx.x;   // d

    float v = 0.0f;
    for (int j = 0; j < 32; j++)
        v += vpart[(((size_t)bi * 32 + j) * KK + k) * DD + t];

    float asum = 0.0f;
    for (int j = 0; j < 128; j++)
        asum += apart[((size_t)bi * 128 + j) * KK + k];

    v -= asum * kmean[(size_t)k * DD + t];

    float sq = v * v;
    sq += __shfl_xor(sq, 1);  sq += __shfl_xor(sq, 2);  sq += __shfl_xor(sq, 4);
    sq += __shfl_xor(sq, 8);  sq += __shfl_xor(sq, 16); sq += __shfl_xor(sq, 32);
    __shared__ float red[4];
    if ((t & 63) == 0) red[t >> 6] = sq;
    __syncthreads();
    float tot = red[0] + red[1] + red[2] + red[3];

    const float EPS = 1e-12f;
    float invn = 1.0f / fmaxf(sqrtf(tot), EPS);
    const float invK = 0.1767766952966369f;  // 1/sqrt(32): global norm after intra-norm
    out[((size_t)bi * KK + k) * DD + t] = v * invn * invK;
}

extern "C" void kernel_launch(void* const* d_in, const int* in_sizes, int n_in,
                              void* d_out, int out_size, void* d_ws, size_t ws_size,
                              hipStream_t stream) {
    const float* x     = (const float*)d_in[0];
    const float* W     = (const float*)d_in[1];
    const float* bias  = (const float*)d_in[2];
    const float* kmean = (const float*)d_in[3];
    float* out = (float*)d_out;

    // ws carve: vpart (512*32*256 f32 = 16.8MB) | apart (2048*32 f32 = 256KB)
    float* vpart = (float*)d_ws;
    float* apart = vpart + (size_t)512 * KK * DD;

    hipLaunchKernelGGL(netvlad_k1, dim3(512), dim3(256), 0, stream,
                       x, W, bias, vpart, apart);
    hipLaunchKernelGGL(netvlad_kC, dim3(BB * KK), dim3(256), 0, stream,
                       vpart, apart, kmean, out);
}

// Round 19
// 67.877 us; speedup vs baseline: 2.7716x; 1.4557x over previous
//
#include <hip/hip_runtime.h>
#include <hip/hip_bf16.h>
#include <math.h>

#define BB 16
#define NN 16384
#define DD 256
#define KK 32

typedef short bf16x8 __attribute__((ext_vector_type(8)));
typedef float f32x4 __attribute__((ext_vector_type(4)));

__device__ inline unsigned pk2(float lo, float hi) {
    __hip_bfloat162 h = __float22bfloat162_rn(make_float2(lo, hi));
    union { __hip_bfloat162 h; unsigned u; } v; v.h = h;
    return v.u;
}
__device__ inline bf16x8 u4bf(uint4 q) {
    union { uint4 u; bf16x8 v; } c; c.u = q; return c.v;
}

// compile-time float4 component select
#define CAE(vv, e) ((e) == 0 ? (vv).x : (e) == 1 ? (vv).y : (e) == 2 ? (vv).z : (vv).w)

// r18 (98.8us, fence-free) with grid 512->256 blocks: 1024 rows/block, 16 subs,
// exactly 1 resident block per CU -> one prologue/epilogue per CU (was two),
// vpart halves (kC reads 8.4MB not 16.8). Epilogue = r11-style 2-step.
// bounds(256,1): 512 unified regs/wave, demand ~296 -> zero spill.
__launch_bounds__(256, 1)
__global__ void netvlad_k1(const float* __restrict__ x,
                           const float* __restrict__ W,
                           const float* __restrict__ bias,
                           float* __restrict__ vpart,
                           float* __restrict__ apart) {
    __shared__ __align__(16) char lds[49152];
    // [0,16384): Wl bf16, byte = k*512 + (dbyte ^ ((k&7)<<4))
    // [16384,49152): xt per-wave 8KB: d*32 + (nbyte ^ (((d>>3)&1)<<4))
    // epilogue: vbuf f32 [32][260] at byte 0

    const int t   = threadIdx.x;
    const int l   = t & 63;
    const int w   = t >> 6;
    const int l15 = l & 15;
    const int lg4 = l >> 4;
    const int bid = blockIdx.x;
    const int b   = bid >> 4;            // batch (16 blocks per batch)
    const int blk = bid & 15;            // 1024-row chunk

    // ---- stage Wl (bf16, swizzled) once ----
    for (int i = 0; i < 8; i++) {
        int f = i * 256 + t;             // float4 index in [0,2048)
        int k = f >> 6, c4 = f & 63;
        float4 wv = ((const float4*)W)[f];
        int byte = k * 512 + ((c4 * 8) ^ ((k & 7) << 4));
        *(uint2*)(lds + byte) = make_uint2(pk2(wv.x, wv.y), pk2(wv.z, wv.w));
    }
    const float cb0 = bias[l15];
    const float cb1 = bias[16 + l15];
    __syncthreads();                     // once; Wl read-only afterwards

    char* xtw = lds + 16384 + w * 8192;

    f32x4 acc0[16], acc1[16];
#pragma unroll
    for (int i = 0; i < 16; i++) { acc0[i] = (f32x4){0,0,0,0}; acc1[i] = (f32x4){0,0,0,0}; }
    float asr0 = 0.f, asr1 = 0.f;

    const float* xbase = x + ((size_t)b * NN + (size_t)blk * 1024) * DD;

    // prologue: prefetch sub-0 row-slices: pf[2ks+h] = x[w*16+l15][ks*32+lg4*8+h*4..]
    float4 pf[16];
    {
        const float* xr = xbase + (size_t)(w * 16 + l15) * DD + lg4 * 8;
#pragma unroll
        for (int ks = 0; ks < 8; ks++) {
            pf[2 * ks]     = *(const float4*)(xr + ks * 32);
            pf[2 * ks + 1] = *(const float4*)(xr + ks * 32 + 4);
        }
    }

    uint4 af0 = make_uint4(0, 0, 0, 0), af1 = make_uint4(0, 0, 0, 0);

#pragma unroll 1
    for (int s = 0; s < 16; s++) {
        const float* xsub = xbase + ((size_t)s * 64 + (size_t)w * 16) * DD;

        // A: issue ca col-loads rows 0-7 (L2/L3-hot: pf stream fetched these lines)
        float4 ca[8];
#pragma unroll
        for (int i = 0; i < 8; i++)
            ca[i] = *(const float4*)(xsub + (size_t)i * DD + l * 4);

        // B: deferred aggregation for sub s-1 (covers ca latency).
        // Same-wave DS in-order: xt writes from C/D of sub s-1 are visible.
        if (s > 0) {
#pragma unroll
            for (int dt = 0; dt < 16; dt++) {
                int d = dt * 16 + l15;
                unsigned sw = ((unsigned)(d >> 3) & 1u) << 4;
                uint2 bl = *(const uint2*)(xtw + d * 32 + ((lg4 * 8) ^ sw));
                bf16x8 bv = u4bf(make_uint4(bl.x, bl.y, 0, 0));
                acc0[dt] = __builtin_amdgcn_mfma_f32_16x16x32_bf16(u4bf(af0), bv, acc0[dt], 0, 0, 0);
                acc1[dt] = __builtin_amdgcn_mfma_f32_16x16x32_bf16(u4bf(af1), bv, acc1[dt], 0, 0, 0);
            }
        }

        // C/D: stage wave-private x^T tile (two 8-row halves, register transpose)
#pragma unroll
        for (int half = 0; half < 2; half++) {
            if (half == 1) {
#pragma unroll
                for (int i = 0; i < 8; i++)
                    ca[i] = *(const float4*)(xsub + (size_t)(8 + i) * DD + l * 4);
            }
#pragma unroll
            for (int e = 0; e < 4; e++) {
                int d = 4 * l + e;
                unsigned sw = ((unsigned)(d >> 3) & 1u) << 4;
                uint4 q;
                q.x = pk2(CAE(ca[0], e), CAE(ca[1], e));
                q.y = pk2(CAE(ca[2], e), CAE(ca[3], e));
                q.z = pk2(CAE(ca[4], e), CAE(ca[5], e));
                q.w = pk2(CAE(ca[6], e), CAE(ca[7], e));
                *(uint4*)(xtw + d * 32 + (((unsigned)(half * 16)) ^ sw)) = q;
            }
        }

        // E: logits mfma(A = x row-frags from pf, B = W^T from Wl)
        f32x4 c0 = (f32x4){cb0, cb0, cb0, cb0};
        f32x4 c1 = (f32x4){cb1, cb1, cb1, cb1};
        {
            const unsigned swk = ((unsigned)(l15 & 7)) << 4;
#pragma unroll
            for (int ks = 0; ks < 8; ks++) {
                uint4 xq;
                xq.x = pk2(pf[2 * ks].x,     pf[2 * ks].y);
                xq.y = pk2(pf[2 * ks].z,     pf[2 * ks].w);
                xq.z = pk2(pf[2 * ks + 1].x, pf[2 * ks + 1].y);
                xq.w = pk2(pf[2 * ks + 1].z, pf[2 * ks + 1].w);
                bf16x8 ax = u4bf(xq);
                bf16x8 w0 = *(const bf16x8*)(lds + l15 * 512        + (((unsigned)(ks * 64 + lg4 * 16)) ^ swk));
                bf16x8 w1 = *(const bf16x8*)(lds + (16 + l15) * 512 + (((unsigned)(ks * 64 + lg4 * 16)) ^ swk));
                c0 = __builtin_amdgcn_mfma_f32_16x16x32_bf16(ax, w0, c0, 0, 0, 0);
                c1 = __builtin_amdgcn_mfma_f32_16x16x32_bf16(ax, w1, c1, 0, 0, 0);
            }
        }

        // F: issue next sub's HBM row-slice prefetch (in flight across softmax+agg)
        if (s < 15) {
            const float* xr = xbase + ((size_t)(s + 1) * 64 + (size_t)(w * 16 + l15)) * DD + lg4 * 8;
#pragma unroll
            for (int ks = 0; ks < 8; ks++) {
                pf[2 * ks]     = *(const float4*)(xr + ks * 32);
                pf[2 * ks + 1] = *(const float4*)(xr + ks * 32 + 4);
            }
        }

        // G: softmax over k=32 (16 lanes x 2 tiles), fully in-register
        float a0v[4], a1v[4];
#pragma unroll
        for (int r = 0; r < 4; r++) {
            float m = fmaxf(c0[r], c1[r]);
            m = fmaxf(m, __shfl_xor(m, 1));
            m = fmaxf(m, __shfl_xor(m, 2));
            m = fmaxf(m, __shfl_xor(m, 4));
            m = fmaxf(m, __shfl_xor(m, 8));
            float p0 = __expf(c0[r] - m), p1 = __expf(c1[r] - m);
            float ss = p0 + p1;
            ss += __shfl_xor(ss, 1);
            ss += __shfl_xor(ss, 2);
            ss += __shfl_xor(ss, 4);
            ss += __shfl_xor(ss, 8);
            float inv = 1.0f / ss;
            a0v[r] = p0 * inv; a1v[r] = p1 * inv;
        }
        asr0 += a0v[0] + a0v[1] + a0v[2] + a0v[3];
        asr1 += a1v[0] + a1v[1] + a1v[2] + a1v[3];
        af0 = make_uint4(pk2(a0v[0], a0v[1]), pk2(a0v[2], a0v[3]), 0, 0);
        af1 = make_uint4(pk2(a1v[0], a1v[1]), pk2(a1v[2], a1v[3]), 0, 0);
    }

    // tail aggregation for sub 15 (same-wave DS in-order guarantees xt visible)
#pragma unroll
    for (int dt = 0; dt < 16; dt++) {
        int d = dt * 16 + l15;
        unsigned sw = ((unsigned)(d >> 3) & 1u) << 4;
        uint2 bl = *(const uint2*)(xtw + d * 32 + ((lg4 * 8) ^ sw));
        bf16x8 bv = u4bf(make_uint4(bl.x, bl.y, 0, 0));
        acc0[dt] = __builtin_amdgcn_mfma_f32_16x16x32_bf16(u4bf(af0), bv, acc0[dt], 0, 0, 0);
        acc1[dt] = __builtin_amdgcn_mfma_f32_16x16x32_bf16(u4bf(af1), bv, acc1[dt], 0, 0, 0);
    }

    // ---- asum: reduce over lg4 groups; per-wave global partials ----
    asr0 += __shfl_xor(asr0, 16);  asr0 += __shfl_xor(asr0, 32);
    asr1 += __shfl_xor(asr1, 16);  asr1 += __shfl_xor(asr1, 32);
    if (l < 16) {
        float* ap = apart + ((size_t)bid * 4 + w) * KK;
        ap[l15]      = asr0;
        ap[16 + l15] = asr1;
    }

    // ---- epilogue: cross-wave v reduce via LDS (Wl/xt dead), 2-step ----
    __syncthreads();
    float* vb = (float*)lds;             // [32][260] f32
    // step 1: waves 0,1 write disjoint (w0: k rows via dt split? -> use w parity)
    if ((w & 1) == 0) {                  // waves 0,2 write... need disjoint: use w<2
    }
    // simple 2-step: waves 0-1 write (disjoint? both cover same region) -> keep
    // r18's serialized ww loop for waves but pairwise: w0 writes, then w1-3 add
    // in 2 rounds (w1|w2 then w3 would still collide). Safe minimal: w0 writes,
    // then odd pair adds serialized as before but only 3 syncs total.
    if (w == 0) {
#pragma unroll
        for (int dt = 0; dt < 16; dt++) {
            int d = dt * 16 + l15;
#pragma unroll
            for (int r = 0; r < 4; r++) {
                int k0 = lg4 * 4 + r;
                vb[k0 * 260 + d]        = acc0[dt][r];
                vb[(16 + k0) * 260 + d] = acc1[dt][r];
            }
        }
    }
    __syncthreads();
    if (w == 1 || w == 2) {
        if (w == 1) {
#pragma unroll
            for (int dt = 0; dt < 16; dt++) {
                int d = dt * 16 + l15;
#pragma unroll
                for (int r = 0; r < 4; r++) {
                    int k0 = lg4 * 4 + r;
                    vb[k0 * 260 + d]        += acc0[dt][r];
                    vb[(16 + k0) * 260 + d] += acc1[dt][r];
                }
            }
        }
    }
    __syncthreads();
    if (w == 2) {
#pragma unroll
        for (int dt = 0; dt < 16; dt++) {
            int d = dt * 16 + l15;
#pragma unroll
            for (int r = 0; r < 4; r++) {
                int k0 = lg4 * 4 + r;
                vb[k0 * 260 + d]        += acc0[dt][r];
                vb[(16 + k0) * 260 + d] += acc1[dt][r];
            }
        }
    }
    __syncthreads();
    if (w == 3) {
#pragma unroll
        for (int dt = 0; dt < 16; dt++) {
            int d = dt * 16 + l15;
#pragma unroll
            for (int r = 0; r < 4; r++) {
                int k0 = lg4 * 4 + r;
                vb[k0 * 260 + d]        += acc0[dt][r];
                vb[(16 + k0) * 260 + d] += acc1[dt][r];
            }
        }
    }
    __syncthreads();
    float* vp = vpart + (size_t)bid * KK * DD;
#pragma unroll
    for (int i = 0; i < 8; i++) {
        int f = i * 256 + t;
        int k = f >> 6, c4 = f & 63;
        f32x4 v4 = *(const f32x4*)&vb[k * 260 + c4 * 4];
        *(f32x4*)&vp[(size_t)k * DD + c4 * 4] = v4;
    }
}

// kC: reduce 16 v-partials + 64 asum-partials, subtract a_sum*k_mean, normalize.
__global__ void netvlad_kC(const float* __restrict__ vpart,
                           const float* __restrict__ apart,
                           const float* __restrict__ kmean,
                           float* __restrict__ out) {
    const int bi = blockIdx.x / KK;
    const int k  = blockIdx.x % KK;
    const int t  = threadIdx.x;   // d

    float v = 0.0f;
    for (int j = 0; j < 16; j++)
        v += vpart[(((size_t)bi * 16 + j) * KK + k) * DD + t];

    float asum = 0.0f;
    for (int j = 0; j < 64; j++)
        asum += apart[((size_t)bi * 64 + j) * KK + k];

    v -= asum * kmean[(size_t)k * DD + t];

    float sq = v * v;
    sq += __shfl_xor(sq, 1);  sq += __shfl_xor(sq, 2);  sq += __shfl_xor(sq, 4);
    sq += __shfl_xor(sq, 8);  sq += __shfl_xor(sq, 16); sq += __shfl_xor(sq, 32);
    __shared__ float red[4];
    if ((t & 63) == 0) red[t >> 6] = sq;
    __syncthreads();
    float tot = red[0] + red[1] + red[2] + red[3];

    const float EPS = 1e-12f;
    float invn = 1.0f / fmaxf(sqrtf(tot), EPS);
    const float invK = 0.1767766952966369f;  // 1/sqrt(32): global norm after intra-norm
    out[((size_t)bi * KK + k) * DD + t] = v * invn * invK;
}

extern "C" void kernel_launch(void* const* d_in, const int* in_sizes, int n_in,
                              void* d_out, int out_size, void* d_ws, size_t ws_size,
                              hipStream_t stream) {
    const float* x     = (const float*)d_in[0];
    const float* W     = (const float*)d_in[1];
    const float* bias  = (const float*)d_in[2];
    const float* kmean = (const float*)d_in[3];
    float* out = (float*)d_out;

    // ws carve: vpart (256*32*256 f32 = 8.4MB) | apart (1024*32 f32 = 128KB)
    float* vpart = (float*)d_ws;
    float* apart = vpart + (size_t)256 * KK * DD;

    hipLaunchKernelGGL(netvlad_k1, dim3(256), dim3(256), 0, stream,
                       x, W, bias, vpart, apart);
    hipLaunchKernelGGL(netvlad_kC, dim3(BB * KK), dim3(256), 0, stream,
                       vpart, apart, kmean, out);
}